// Round 2
// baseline (1555.564 us; speedup 1.0000x reference)
//
#include <hip/hip_runtime.h>
#include <hip/hip_fp16.h>

#define BB 16
#define TT 1024
#define DD 8704
#define RR 256
#define HH 72
#define H3 216
#define TAU 12
#define KSTEPS 136   // 8704 / 64

typedef _Float16 f16;
typedef _Float16 f16x8 __attribute__((ext_vector_type(8)));
typedef float f32x4 __attribute__((ext_vector_type(4)));

__device__ __forceinline__ float sigmoidf_(float x){ return 1.0f/(1.0f+__expf(-x)); }
__device__ __forceinline__ float tanhf_(float x){
  x = fminf(15.0f, fmaxf(-15.0f, x));
  float t = __expf(2.0f*x);
  return (t-1.0f)/(t+1.0f);
}

// ---------------------------------------------------------------------------
// Kernel A: W = w_ih @ w_dr  [216 x 8704] (zero-padded to 256 rows), stored
// fp16 in MFMA-B-fragment packed order:
//   off = ((((nblock*136 + ks)*2 + ksub)*8 + ntile)*64 + lane)*8 + jj
//   n = nblock*128 + ntile*16 + (lane&15), k = ks*64 + ksub*32 + (lane>>4)*8 + jj
// so gemm's B staging is pure linear global_load_lds (wave-uniform base +
// lane*16B), no swizzle needed.
// ---------------------------------------------------------------------------
__global__ __launch_bounds__(256) void build_w_kernel(const float* __restrict__ w_ih,
        const float* __restrict__ w_dr, f16* __restrict__ Wp){
  const int tid = threadIdx.x;
  const int ks  = blockIdx.x >> 6;      // 0..135
  const int ng  = blockIdx.x & 63;      // 0..63  (n group of 4)
  const int kl  = tid & 63;             // 0..63
  const int ni  = tid >> 6;             // 0..3
  const int n   = ng*4 + ni;            // 0..255
  const int k   = ks*64 + kl;
  float acc = 0.f;
  if (n < H3){
    const float* wi = w_ih + n*RR;
    const float* wd = w_dr + k;
    #pragma unroll 4
    for (int r=0; r<RR; ++r) acc += wi[r] * wd[(size_t)r*DD];
  }
  const int ksub = kl >> 5, g = (kl>>3)&3, jj = kl&7;
  const int nblock = n >> 7, ntile = (n>>4)&7, ncol = n & 15;
  const int lane_ = g*16 + ncol;
  size_t off = (((((size_t)nblock*KSTEPS + ks)*2 + ksub)*8 + ntile)*64 + lane_)*8 + jj;
  Wp[off] = (f16)acc;
}

// bvec = b_ih + w_ih @ b_dr ; one block per output row, 64-lane k-split.
__global__ __launch_bounds__(64) void build_bvec_kernel(const float* __restrict__ w_ih,
        const float* __restrict__ b_dr, const float* __restrict__ b_ih,
        float* __restrict__ bvec){
  const int n = blockIdx.x, l = threadIdx.x;
  float a = 0.f;
  for (int r=l; r<RR; r+=64) a += w_ih[n*RR+r]*b_dr[r];
  #pragma unroll
  for (int off=32; off>0; off>>=1) a += __shfl_down(a, off);
  if (l==0) bvec[n] = a + b_ih[n];
}

// ---------------------------------------------------------------------------
// Kernel B: xp[16384,216] = x @ W^T + bvec   (fp16 MFMA, fp32 accum)
// BM=128, BN=128, BK=64. grid = 256: mb = bid&127, nb = bid>>7, so the two
// blocks sharing an A-panel are 128 apart -> same XCD (128%8==0) and
// co-resident (256 blocks on 256 CUs) -> A-panel read from HBM once, partner
// hits L2/L3.
// A: fp32 global -> reg -> cvt f16 -> XOR-swizzled ds_write_b128; read side
//    applies the same (row&7)<<4 16B-granule involution -> conflict-free.
// B: packed fp16 -> global_load_lds width 16, linear.
// 8 waves as 4M x 2N; wave tile 32x64; 16 MFMA / k-step / wave. LDS = 64 KB.
// ---------------------------------------------------------------------------
__global__ __launch_bounds__(512) void gemm_xp_kernel(const float* __restrict__ x,
     const f16* __restrict__ Wp, const float* __restrict__ bvec, float* __restrict__ xp){
  __shared__ f16 Ab[2][128*64];
  __shared__ f16 Bb[2][128*64];
  const int tid  = threadIdx.x;
  const int lane = tid & 63;
  const int wid  = tid >> 6;
  const int wm   = wid >> 1;            // 0..3
  const int wn   = wid & 1;             // 0..1
  const int mb   = blockIdx.x & 127;
  const int nb   = blockIdx.x >> 7;

  const int arow = tid >> 2;
  const int aqr  = tid & 3;
  const float* aptr = x + (size_t)(mb*128 + arow)*DD + aqr*16;
  const int swz  = (arow & 7) << 4;
  const int awb0 = arow*128 + ((aqr*32 +  0) ^ swz);   // byte offsets in A buf
  const int awb1 = arow*128 + ((aqr*32 + 16) ^ swz);

  f32x4 areg[4];
  f32x4 acc[2][4];
  #pragma unroll
  for (int i=0;i<2;i++)
    #pragma unroll
    for (int j=0;j<4;j++) acc[i][j] = (f32x4){0.f,0.f,0.f,0.f};

  auto loadA = [&](int ks){
    const f32x4* p = (const f32x4*)(aptr + ks*64);
    areg[0]=p[0]; areg[1]=p[1]; areg[2]=p[2]; areg[3]=p[3];
  };
  auto writeA = [&](int buf){
    f16x8 v0, v1;
    #pragma unroll
    for (int i=0;i<4;i++){
      v0[i]   = (f16)areg[0][i];
      v0[4+i] = (f16)areg[1][i];
      v1[i]   = (f16)areg[2][i];
      v1[4+i] = (f16)areg[3][i];
    }
    char* base = (char*)&Ab[buf][0];
    *(f16x8*)(base + awb0) = v0;
    *(f16x8*)(base + awb1) = v1;
  };
  auto stageB = [&](int ks, int buf){
    const f16* g = Wp + ((size_t)(nb*KSTEPS + ks)*1024 + tid)*8;
    __builtin_amdgcn_global_load_lds((const __attribute__((address_space(1))) void*)g,
          (__attribute__((address_space(3))) void*)&Bb[buf][tid*8], 16, 0, 0);
    __builtin_amdgcn_global_load_lds((const __attribute__((address_space(1))) void*)(g + 512*8),
          (__attribute__((address_space(3))) void*)&Bb[buf][(tid+512)*8], 16, 0, 0);
  };

  loadA(0); stageB(0, 0); writeA(0);
  __syncthreads();

  #pragma unroll 1
  for (int ks=0; ks<KSTEPS; ++ks){
    const int cur = ks & 1, nxt = cur ^ 1;
    if (ks+1 < KSTEPS){ loadA(ks+1); stageB(ks+1, nxt); }
    const char* abase = (const char*)&Ab[cur][0];
    const f16*  bbase = &Bb[cur][0];
    #pragma unroll
    for (int ksub=0; ksub<2; ++ksub){
      f16x8 af[2], bf[4];
      #pragma unroll
      for (int mf=0; mf<2; ++mf){
        int row = wm*32 + mf*16 + (lane & 15);
        int g   = lane >> 4;
        int byt = row*128 + ((ksub*64 + g*16) ^ ((row&7)<<4));
        af[mf] = *(const f16x8*)(abase + byt);
      }
      #pragma unroll
      for (int nf=0; nf<4; ++nf){
        int idx = ((ksub*8 + wn*4 + nf)*64 + lane)*8;
        bf[nf] = *(const f16x8*)(bbase + idx);
      }
      #pragma unroll
      for (int mf=0; mf<2; ++mf)
        #pragma unroll
        for (int nf=0; nf<4; ++nf)
          acc[mf][nf] = __builtin_amdgcn_mfma_f32_16x16x32_f16(af[mf], bf[nf], acc[mf][nf], 0, 0, 0);
    }
    if (ks+1 < KSTEPS) writeA(nxt);
    __syncthreads();
  }

  // epilogue: D layout col = lane&15, row = (lane>>4)*4 + qi  [m89-verified]
  const int row0 = mb*128 + wm*32;
  const int col0 = nb*128 + wn*64;
  #pragma unroll
  for (int nf=0; nf<4; ++nf){
    int n = col0 + nf*16 + (lane & 15);
    if (n < H3){
      float bv = bvec[n];
      #pragma unroll
      for (int mf=0; mf<2; ++mf){
        int mbase = row0 + mf*16 + (lane>>4)*4;
        #pragma unroll
        for (int qi=0; qi<4; ++qi)
          xp[(size_t)(mbase+qi)*H3 + n] = acc[mf][nf][qi] + bv;
      }
    }
  }
}

// ---------------------------------------------------------------------------
// Kernel C: GRU scan — ONE barrier per step.
// One block per batch, 256 threads = 4 waves. Wave w, lane l (l<54 active):
//   unit = w*18 + l/3  (0..71),  gate = l%3 (0=r,1=z,2=n),  row = gate*72+unit.
// Each active lane: w_hh[row,:] in 72 VGPRs, computes hp[row] from the
// h broadcast (double-buffered LDS, read buf[t&1]). The r/z/n exchange for a
// unit is intra-wave: lanes 3u,3u+1,3u+2 -> two __shfl's, no LDS round-trip,
// no second barrier. h_old lives in the lead lane's register. Lead lane
// writes h_new to buf[(t+1)&1] (no read/write overlap => single barrier).
// ---------------------------------------------------------------------------
__global__ __launch_bounds__(256) void gru_kernel(const float* __restrict__ xp,
        const float* __restrict__ w_hh, const float* __restrict__ b_hh,
        float* __restrict__ hseq){
  const int b = blockIdx.x, tid = threadIdx.x;
  const int w = tid >> 6, l = tid & 63;
  const bool active = (l < 54);
  const int gate = l % 3;
  const int unit = w*18 + l/3;          // <72 when active
  const int row  = gate*72 + unit;      // <216 when active
  const bool lead = active && (gate == 0);

  __shared__ __align__(16) float h_lds[2][HH];

  float whh[HH];
  float bhh = 0.f;
  if (active){
    #pragma unroll
    for (int k=0;k<HH;k++) whh[k] = w_hh[row*HH + k];
    bhh = b_hh[row];
  }
  if (tid < HH) h_lds[0][tid] = 0.f;
  __syncthreads();

  float h_reg = 0.f;
  float xv = active ? xp[(size_t)(b*TT)*H3 + row] : 0.f;

  for (int t=0; t<TT; ++t){
    const float4* h4 = (const float4*)h_lds[t&1];
    float a0=0.f,a1=0.f,a2=0.f,a3=0.f;
    #pragma unroll
    for (int kk=0; kk<HH/4; ++kk){
      float4 hv = h4[kk];
      a0 += whh[4*kk+0]*hv.x;
      a1 += whh[4*kk+1]*hv.y;
      a2 += whh[4*kk+2]*hv.z;
      a3 += whh[4*kk+3]*hv.w;
    }
    float hp = (a0+a1)+(a2+a3) + bhh;
    float v  = xv + hp;                  // pre-activation for gates r,z
    float xv_cur = xv;
    if (active && t+1 < TT)              // prefetch next step's xp slice
      xv = xp[(size_t)(b*TT + t+1)*H3 + row];

    float vz   = __shfl(v,      l + 1);  // z pre-act  (lane 3u+1)
    float hpn  = __shfl(hp,     l + 2);  // hp_n       (lane 3u+2)
    float xnv  = __shfl(xv_cur, l + 2);  // x_n        (lane 3u+2)
    if (lead){
      float r  = sigmoidf_(v);
      float z  = sigmoidf_(vz);
      float n  = tanhf_(xnv + r*hpn);
      float hn = (1.f - z)*n + z*h_reg;
      h_reg = hn;
      h_lds[(t+1)&1][unit] = hn;
      hseq[((size_t)b*TT + t)*HH + unit] = hn;
    }
    __syncthreads();
  }
}

// ---------------------------------------------------------------------------
// Kernel D: q = hseq @ w_reg^T + b_reg, sitp windows, head. One block / batch.
// ---------------------------------------------------------------------------
__global__ __launch_bounds__(256) void head_kernel(const float* __restrict__ hseq,
      const float* __restrict__ w_reg, const float* __restrict__ b_reg,
      const int* __restrict__ x_len,
      const float* __restrict__ nw1, const float* __restrict__ nb1,
      const float* __restrict__ nw2, const float* __restrict__ nb2,
      const float* __restrict__ lw,  const float* __restrict__ lb,
      float* __restrict__ out){
  const int b = blockIdx.x, tid = threadIdx.x;
  __shared__ __align__(16) float wr[HH];
  __shared__ float q[TT], wv[TT], wq[TT];
  __shared__ float red[4];
  if (tid < HH) wr[tid] = w_reg[tid];
  __syncthreads();
  const int len = x_len[b];
  const float br = b_reg[0];

  #pragma unroll
  for (int i=0;i<4;i++){
    int t = tid + i*256;
    const float4* h4 = (const float4*)(hseq + ((size_t)b*TT + t)*HH);
    const float4* w4 = (const float4*)wr;
    float s = br;
    #pragma unroll
    for (int kk=0; kk<HH/4; ++kk){
      float4 hv=h4[kk], ww=w4[kk];
      s += hv.x*ww.x + hv.y*ww.y + hv.z*ww.z + hv.w*ww.w;
    }
    q[t] = s;
    bool valid = t < len;
    float w_ = valid ? __expf(-s) : 0.f;
    wv[t] = w_; wq[t] = w_*s;
  }
  __syncthreads();

  float partial = 0.f;
  #pragma unroll
  for (int i=0;i<4;i++){
    int t = tid + i*256;
    if (t < len){
      float xmin = q[t];
      int s0 = t-TAU+1; if (s0 < 0) s0 = 0;
      for (int s=s0; s<t; ++s) xmin = fminf(xmin, q[s]);
      int e = t+TAU-1; if (e > TT-1) e = TT-1;
      float num=0.f, den=0.f;
      for (int s=t; s<=e; ++s){ num += wq[s]; den += wv[s]; }
      float y = den > 0.f ? num/fmaxf(den, 1e-30f) : 0.f;
      partial += 0.5f*y + 0.5f*xmin;   // GAMMA = 0.5
    }
  }
  #pragma unroll
  for (int off=32; off>0; off>>=1) partial += __shfl_down(partial, off);
  if ((tid & 63) == 0) red[tid>>6] = partial;
  __syncthreads();
  if (tid == 0){
    float tot = red[0]+red[1]+red[2]+red[3];
    float rel = sigmoidf_(tot/(float)len);
    float map = sigmoidf_(nw1[0]*rel + nb1[0])*nw2[0] + nb2[0];
    float alg = lw[0]*map + lb[0];
    out[b] = rel; out[BB+b] = map; out[2*BB+b] = alg;
  }
}

// ---------------------------------------------------------------------------
extern "C" void kernel_launch(void* const* d_in, const int* in_sizes, int n_in,
                              void* d_out, int out_size, void* d_ws, size_t ws_size,
                              hipStream_t stream){
  const float* x     = (const float*)d_in[0];
  const int*   x_len = (const int*)  d_in[1];
  const float* w_dr  = (const float*)d_in[2];
  const float* b_dr  = (const float*)d_in[3];
  const float* w_ih  = (const float*)d_in[4];
  const float* w_hh  = (const float*)d_in[5];
  const float* b_ih  = (const float*)d_in[6];
  const float* b_hh  = (const float*)d_in[7];
  const float* w_reg = (const float*)d_in[8];
  const float* b_reg = (const float*)d_in[9];
  const float* nw1   = (const float*)d_in[10];
  const float* nb1   = (const float*)d_in[11];
  const float* nw2   = (const float*)d_in[12];
  const float* nb2   = (const float*)d_in[13];
  const float* lw    = (const float*)d_in[14];
  const float* lb    = (const float*)d_in[15];
  float* out = (float*)d_out;

  char* ws = (char*)d_ws;
  f16*   Wp   = (f16*)ws;                   // 2,228,224 f16 = 4,456,448 B
  float* bvec = (float*)(ws + 4456448);     // 216 f32 (padded to 1 KB)
  float* xp   = (float*)(ws + 4457472);     // 16384*216 f32 = 14,155,776 B
  float* hseq = (float*)(ws + 18613248);    // 16*1024*72 f32 = 4,718,592 B
                                            // total ~23.3 MB of d_ws

  build_w_kernel   <<<KSTEPS*64, 256, 0, stream>>>(w_ih, w_dr, Wp);
  build_bvec_kernel<<<H3, 64, 0, stream>>>(w_ih, b_dr, b_ih, bvec);
  gemm_xp_kernel   <<<256, 512, 0, stream>>>(x, Wp, bvec, xp);
  gru_kernel       <<<BB, 256, 0, stream>>>(xp, w_hh, b_hh, hseq);
  head_kernel      <<<BB, 256, 0, stream>>>(hseq, w_reg, b_reg, x_len,
                                            nw1, nb1, nw2, nb2, lw, lb, out);
}